// Round 1
// baseline (512.510 us; speedup 1.0000x reference)
//
#include <hip/hip_runtime.h>

// ---------------- problem constants ----------------
#define NB 32
#define C 128
#define H 56
#define W 56
#define HWSZ (H*W)                 // 3136
#define ELTS (NB*C*HWSZ)           // 12,845,056
#define NHW (NB*HWSZ)              // 100,352 per-channel count
#define HP 59                      // padded rows (56 + 2 pad + 1 safety)
#define WP 64                      // padded cols

typedef __attribute__((ext_vector_type(8))) short bf16x8;
typedef __attribute__((ext_vector_type(4))) float f32x4;

// ---------------- meta (float offsets) ----------------
#define SLOT_SX 0
#define SLOT_SW1 1
#define SLOT_SW2 2
#define SLOT_SA2 3
#define SUM1 8
#define SSQ1 136
#define SCALE1 264
#define SHIFT1 392
#define SUM2 520
#define SSQ2 648
#define SCALE2 776
#define SHIFT2 904

// ---------------- workspace byte offsets ----------------
#define META_OFF 0ull
#define META_BYTES 8192ull
#define XQ_OFF 8192ull
#define XQ_BYTES ((unsigned long long)NB*HP*WP*C*2ull)   // 30,932,992
#define A2Q_OFF (XQ_OFF + XQ_BYTES)
#define Y_OFF (A2Q_OFF + XQ_BYTES)
#define Y_BYTES ((unsigned long long)ELTS*4ull)
#define W1Q_OFF (Y_OFF + Y_BYTES)
#define WQ_BYTES (9ull*128*128*2)
#define W2Q_OFF (W1Q_OFF + WQ_BYTES)
// total ~113.8 MB

__device__ __forceinline__ short f2bf(float f) {
    // values are integers |v|<=127 -> exact in bf16 via truncation
    return (short)(__float_as_uint(f) >> 16);
}

// ---------------- absmax reduction ----------------
__global__ void absmax_kernel(const float* __restrict__ p, int n4, unsigned* __restrict__ slot) {
    __shared__ float red[256];
    float m = 0.f;
    int stride = gridDim.x * blockDim.x;
    for (int i = blockIdx.x * blockDim.x + threadIdx.x; i < n4; i += stride) {
        f32x4 v = ((const f32x4*)p)[i];
        m = fmaxf(m, fmaxf(fmaxf(fabsf(v.x), fabsf(v.y)), fmaxf(fabsf(v.z), fabsf(v.w))));
    }
    red[threadIdx.x] = m;
    __syncthreads();
    for (int s = 128; s > 0; s >>= 1) {
        if (threadIdx.x < s) red[threadIdx.x] = fmaxf(red[threadIdx.x], red[threadIdx.x + s]);
        __syncthreads();
    }
    if (threadIdx.x == 0) atomicMax(slot, __float_as_uint(red[0]));
}

// ---------------- weight quant + layout [tap][co][ci] ----------------
__global__ void quant_w_kernel(const float* __restrict__ w, const float* __restrict__ meta,
                               int slot, short* __restrict__ wq) {
    int idx = blockIdx.x * 256 + threadIdx.x;   // 0..16383
    int co = idx >> 7, ci = idx & 127;
    float s = __uint_as_float(((const unsigned*)meta)[slot]) + 1e-12f;
    float qs = 127.f / s;
    const float* src = w + ((size_t)(co * 128 + ci)) * 9;
    #pragma unroll
    for (int tap = 0; tap < 9; ++tap) {
        float q = rintf(src[tap] * qs);
        wq[((size_t)tap * 128 + co) * 128 + ci] = f2bf(q);
    }
}

// ---------------- quantize (+optional BN/ReLU) + transpose to padded NHWC bf16 ----------------
// mode 0: dst = round(src/s*127)            (src = x, NCHW fp32)
// mode 1: dst = round(relu(src*sc+sh)/s*127)
__global__ void quant_transpose_kernel(const float* __restrict__ src, const float* __restrict__ meta,
                                       int slot, const float* __restrict__ scale,
                                       const float* __restrict__ shift,
                                       short* __restrict__ dst, int mode) {
    __shared__ float tile[128][57];
    int h = blockIdx.x, n = blockIdx.y, t = threadIdx.x;
    int ci = t >> 1, seg = (t & 1) * 28;
    const float* row = src + (((size_t)(n * C + ci)) * H + h) * W + seg;
    float sc = 1.f, sh = 0.f;
    if (mode) { sc = scale[ci]; sh = shift[ci]; }
    #pragma unroll
    for (int j = 0; j < 28; j += 4) {
        f32x4 v = *(const f32x4*)(row + j);
        if (mode) {
            v.x = fmaxf(v.x * sc + sh, 0.f);
            v.y = fmaxf(v.y * sc + sh, 0.f);
            v.z = fmaxf(v.z * sc + sh, 0.f);
            v.w = fmaxf(v.w * sc + sh, 0.f);
        }
        tile[ci][seg + j + 0] = v.x;
        tile[ci][seg + j + 1] = v.y;
        tile[ci][seg + j + 2] = v.z;
        tile[ci][seg + j + 3] = v.w;
    }
    __syncthreads();
    float s = __uint_as_float(((const unsigned*)meta)[slot]) + 1e-12f;
    float qs = 127.f / s;
    int w = t & 63, cq = t >> 6;
    if (w < 56) {
        short* d = dst + (((size_t)n * HP + (h + 1)) * WP + (w + 1)) * C + cq * 32;
        #pragma unroll
        for (int jj = 0; jj < 4; ++jj) {
            bf16x8 v;
            #pragma unroll
            for (int j = 0; j < 8; ++j) {
                float q = rintf(tile[cq * 32 + jj * 8 + j][w] * qs);
                v[j] = f2bf(q);
            }
            *(bf16x8*)(d + jj * 8) = v;
        }
    }
}

// ---------------- conv 3x3 as implicit-GEMM MFMA ----------------
// xq: padded NHWC bf16 integer codes; wq: [tap][co][ci]; y: NCHW fp32 (real units)
__global__ __launch_bounds__(256) void conv_mfma_kernel(
        const short* __restrict__ xq, const short* __restrict__ wq,
        float* __restrict__ y, const float* __restrict__ meta, int slot_in, int slot_w) {
    __shared__ __align__(16) unsigned char lds[68 * 256];  // [w''][ci] bf16, XOR-swizzled
    int h = blockIdx.x, n = blockIdx.y;
    int t = threadIdx.x, lane = t & 63, wv = t >> 6;
    int co0 = wv * 32;
    int l15 = lane & 15, lg = lane >> 4;
    f32x4 acc[2][4] = {};

    const short* slab0 = xq + ((size_t)(n * HP + h) * WP) * C;  // row h'=h (+dh rows)

    for (int dh = 0; dh < 3; ++dh) {
        __syncthreads();
        const char* g = (const char*)(slab0 + (size_t)dh * WP * C);
        #pragma unroll
        for (int i = 0; i < 4; ++i) {
            int G = (i * 256 + t) * 16;
            bf16x8 v = *(const bf16x8*)(g + G);
            int L = G ^ (((G >> 8) & 7) << 4);
            *(bf16x8*)(lds + L) = v;
        }
        __syncthreads();
        for (int dw = 0; dw < 3; ++dw) {
            const short* wtap = wq + (size_t)(dh * 3 + dw) * 128 * 128;
            #pragma unroll
            for (int cc = 0; cc < 4; ++cc) {
                int kb = cc * 32 + lg * 8;
                bf16x8 a0 = *(const bf16x8*)(wtap + (co0 + l15) * 128 + kb);
                bf16x8 a1 = *(const bf16x8*)(wtap + (co0 + 16 + l15) * 128 + kb);
                #pragma unroll
                for (int fj = 0; fj < 4; ++fj) {
                    int wpp = fj * 16 + l15 + dw;
                    int P = wpp * 256 + cc * 64 + lg * 16;
                    bf16x8 b = *(const bf16x8*)(lds + (P ^ ((wpp & 7) << 4)));
                    acc[0][fj] = __builtin_amdgcn_mfma_f32_16x16x32_bf16(a0, b, acc[0][fj], 0, 0, 0);
                    acc[1][fj] = __builtin_amdgcn_mfma_f32_16x16x32_bf16(a1, b, acc[1][fj], 0, 0, 0);
                }
            }
        }
    }

    float s_in = __uint_as_float(((const unsigned*)meta)[slot_in]) + 1e-12f;
    float s_w  = __uint_as_float(((const unsigned*)meta)[slot_w]) + 1e-12f;
    float dq = s_in * s_w * (1.f / 16129.f);
    #pragma unroll
    for (int ai = 0; ai < 2; ++ai) {
        #pragma unroll
        for (int fj = 0; fj < 4; ++fj) {
            int wo = fj * 16 + l15;
            if (wo < 56) {
                #pragma unroll
                for (int r = 0; r < 4; ++r) {
                    int co = co0 + ai * 16 + lg * 4 + r;
                    y[(((size_t)n * C + co) * H + h) * W + wo] = acc[ai][fj][r] * dq;
                }
            }
        }
    }
}

// ---------------- BN batch stats ----------------
__global__ void bn_stats_kernel(const float* __restrict__ y, float* __restrict__ meta,
                                int sum_off, int ssq_off) {
    __shared__ float r1[256], r2[256];
    int c = blockIdx.x, n = blockIdx.y, t = threadIdx.x;
    const f32x4* p = (const f32x4*)(y + ((size_t)(n * C + c)) * HWSZ);
    float s = 0.f, q = 0.f;
    for (int i = t; i < HWSZ / 4; i += 256) {
        f32x4 v = p[i];
        s += v.x + v.y + v.z + v.w;
        q += v.x * v.x + v.y * v.y + v.z * v.z + v.w * v.w;
    }
    r1[t] = s; r2[t] = q;
    __syncthreads();
    for (int k = 128; k > 0; k >>= 1) {
        if (t < k) { r1[t] += r1[t + k]; r2[t] += r2[t + k]; }
        __syncthreads();
    }
    if (t == 0) {
        atomicAdd(&meta[sum_off + c], r1[0]);
        atomicAdd(&meta[ssq_off + c], r2[0]);
    }
}

__global__ void bn_finalize_kernel(float* __restrict__ meta, int sum_off, int ssq_off,
                                   int scale_off, int shift_off,
                                   const float* __restrict__ gamma, const float* __restrict__ beta) {
    int c = threadIdx.x;
    if (c < 128) {
        float mean = meta[sum_off + c] * (1.f / NHW);
        float var = meta[ssq_off + c] * (1.f / NHW) - mean * mean;
        float istd = rsqrtf(var + 1e-5f);
        float sc = gamma[c] * istd;
        meta[scale_off + c] = sc;
        meta[shift_off + c] = beta[c] - mean * sc;
    }
}

// ---------------- absmax of relu(y*sc+sh) ----------------
__global__ void bnrelu_absmax_kernel(const float* __restrict__ y, const float* __restrict__ meta,
                                     int scale_off, int shift_off, unsigned* __restrict__ slot) {
    __shared__ float red[256];
    int c = blockIdx.x, n = blockIdx.y, t = threadIdx.x;
    float sc = meta[scale_off + c], sh = meta[shift_off + c];
    const f32x4* p = (const f32x4*)(y + ((size_t)(n * C + c)) * HWSZ);
    float m = 0.f;
    for (int i = t; i < HWSZ / 4; i += 256) {
        f32x4 v = p[i];
        m = fmaxf(m, fmaxf(fmaxf(v.x * sc + sh, v.y * sc + sh),
                           fmaxf(v.z * sc + sh, v.w * sc + sh)));
    }
    red[t] = m;
    __syncthreads();
    for (int k = 128; k > 0; k >>= 1) {
        if (t < k) red[t] = fmaxf(red[t], red[t + k]);
        __syncthreads();
    }
    if (t == 0) atomicMax(slot, __float_as_uint(fmaxf(red[0], 0.f)));
}

// ---------------- final: out = relu(y*sc+sh + x) ----------------
__global__ void final_kernel(const float* __restrict__ y, const float* __restrict__ x,
                             const float* __restrict__ meta, float* __restrict__ out) {
    int stride = gridDim.x * blockDim.x;
    for (int i = blockIdx.x * blockDim.x + threadIdx.x; i < ELTS / 4; i += stride) {
        int c = ((i * 4) / HWSZ) & 127;
        float sc = meta[SCALE2 + c], sh = meta[SHIFT2 + c];
        f32x4 v = ((const f32x4*)y)[i];
        f32x4 xi = ((const f32x4*)x)[i];
        f32x4 o;
        o.x = fmaxf(v.x * sc + sh + xi.x, 0.f);
        o.y = fmaxf(v.y * sc + sh + xi.y, 0.f);
        o.z = fmaxf(v.z * sc + sh + xi.z, 0.f);
        o.w = fmaxf(v.w * sc + sh + xi.w, 0.f);
        ((f32x4*)out)[i] = o;
    }
}

extern "C" void kernel_launch(void* const* d_in, const int* in_sizes, int n_in,
                              void* d_out, int out_size, void* d_ws, size_t ws_size,
                              hipStream_t stream) {
    const float* x      = (const float*)d_in[0];
    const float* w1     = (const float*)d_in[1];
    const float* gamma1 = (const float*)d_in[2];
    const float* beta1  = (const float*)d_in[3];
    const float* w2     = (const float*)d_in[4];
    const float* gamma2 = (const float*)d_in[5];
    const float* beta2  = (const float*)d_in[6];
    float* out = (float*)d_out;
    char* ws = (char*)d_ws;

    float* meta = (float*)(ws + META_OFF);
    unsigned* metau = (unsigned*)meta;
    short* xq  = (short*)(ws + XQ_OFF);
    short* a2q = (short*)(ws + A2Q_OFF);
    float* y   = (float*)(ws + Y_OFF);
    short* w1q = (short*)(ws + W1Q_OFF);
    short* w2q = (short*)(ws + W2Q_OFF);

    hipMemsetAsync(ws + META_OFF, 0, META_BYTES, stream);
    hipMemsetAsync(ws + XQ_OFF, 0, XQ_BYTES, stream);
    hipMemsetAsync(ws + A2Q_OFF, 0, XQ_BYTES, stream);

    absmax_kernel<<<1024, 256, 0, stream>>>(x, ELTS / 4, metau + SLOT_SX);
    absmax_kernel<<<64, 256, 0, stream>>>(w1, 147456 / 4, metau + SLOT_SW1);
    absmax_kernel<<<64, 256, 0, stream>>>(w2, 147456 / 4, metau + SLOT_SW2);

    quant_w_kernel<<<64, 256, 0, stream>>>(w1, meta, SLOT_SW1, w1q);
    quant_w_kernel<<<64, 256, 0, stream>>>(w2, meta, SLOT_SW2, w2q);

    dim3 ghn(56, 32);
    quant_transpose_kernel<<<ghn, 256, 0, stream>>>(x, meta, SLOT_SX, nullptr, nullptr, xq, 0);

    conv_mfma_kernel<<<ghn, 256, 0, stream>>>(xq, w1q, y, meta, SLOT_SX, SLOT_SW1);

    dim3 gcn(128, 32);
    bn_stats_kernel<<<gcn, 256, 0, stream>>>(y, meta, SUM1, SSQ1);
    bn_finalize_kernel<<<1, 128, 0, stream>>>(meta, SUM1, SSQ1, SCALE1, SHIFT1, gamma1, beta1);
    bnrelu_absmax_kernel<<<gcn, 256, 0, stream>>>(y, meta, SCALE1, SHIFT1, metau + SLOT_SA2);

    quant_transpose_kernel<<<ghn, 256, 0, stream>>>(y, meta, SLOT_SA2, meta + SCALE1, meta + SHIFT1, a2q, 1);

    conv_mfma_kernel<<<ghn, 256, 0, stream>>>(a2q, w2q, y, meta, SLOT_SA2, SLOT_SW2);

    bn_stats_kernel<<<gcn, 256, 0, stream>>>(y, meta, SUM2, SSQ2);
    bn_finalize_kernel<<<1, 128, 0, stream>>>(meta, SUM2, SSQ2, SCALE2, SHIFT2, gamma2, beta2);

    final_kernel<<<2048, 256, 0, stream>>>(y, x, meta, out);
}

// Round 2
// 499.251 us; speedup vs baseline: 1.0266x; 1.0266x over previous
//
#include <hip/hip_runtime.h>

// ---------------- problem constants ----------------
#define NB 32
#define C 128
#define H 56
#define W 56
#define HWSZ (H*W)                 // 3136
#define ELTS (NB*C*HWSZ)           // 12,845,056
#define NHW (NB*HWSZ)              // 100,352 per-channel count
#define HP 59                      // padded rows (h' = 0..58, data at 1..56)
#define SLAB 16384                 // bytes per (n,h') slab: 64 w' * 128 c * 2B

typedef __attribute__((ext_vector_type(8))) short bf16x8;
typedef __attribute__((ext_vector_type(4))) short short4v;
typedef __attribute__((ext_vector_type(4))) float f32x4;

// ---------------- meta (float offsets) ----------------
#define SLOT_SX 0
#define SLOT_SW1 1
#define SLOT_SW2 2
#define SLOT_SA2 3
#define SUM1 8
#define SSQ1 136
#define MAXE1 264
#define MAXNEG1 392
#define SCALE1 520
#define SHIFT1 648
#define SUM2 776
#define SSQ2 904
#define MAXE2 1032
#define MAXNEG2 1160
#define SCALE2 1288
#define SHIFT2 1416

// ---------------- workspace byte offsets ----------------
#define META_OFF 0ull
#define META_BYTES 8192ull
#define XQ_OFF 8192ull
#define XQ_BYTES ((unsigned long long)NB*HP*SLAB)      // 30,932,992
#define A2Q_OFF (XQ_OFF + XQ_BYTES)
#define Y1_OFF (A2Q_OFF + XQ_BYTES)
#define Y_BYTES ((unsigned long long)ELTS*2ull)        // 25,690,112 (bf16)
#define Y2_OFF (Y1_OFF + Y_BYTES)
#define W1Q_OFF (Y2_OFF + Y_BYTES)
#define WQ_BYTES (9ull*128*128*2)
#define W2Q_OFF (W1Q_OFF + WQ_BYTES)
// total ~108.6 MiB

__device__ __forceinline__ short f2bf(float f) {           // trunc: exact for int codes
    return (short)(__float_as_uint(f) >> 16);
}
__device__ __forceinline__ short f2bf_rne(float f) {       // round-nearest-even
    unsigned u = __float_as_uint(f);
    return (short)((u + 0x7FFFu + ((u >> 16) & 1u)) >> 16);
}
__device__ __forceinline__ float bf2f(short s) {
    return __uint_as_float(((unsigned)(unsigned short)s) << 16);
}
// monotone float->unsigned encoding for atomicMax (handles negatives)
__device__ __forceinline__ unsigned fenc(float f) {
    unsigned u = __float_as_uint(f);
    return (u & 0x80000000u) ? ~u : (u | 0x80000000u);
}
__device__ __forceinline__ float fdec(unsigned e) {
    unsigned u = (e & 0x80000000u) ? (e ^ 0x80000000u) : ~e;
    return __uint_as_float(u);
}

// ---------------- absmax reduction ----------------
__global__ void absmax_kernel(const float* __restrict__ p, int n4, unsigned* __restrict__ slot) {
    __shared__ float red[256];
    float m = 0.f;
    int stride = gridDim.x * blockDim.x;
    for (int i = blockIdx.x * blockDim.x + threadIdx.x; i < n4; i += stride) {
        f32x4 v = ((const f32x4*)p)[i];
        m = fmaxf(m, fmaxf(fmaxf(fabsf(v.x), fabsf(v.y)), fmaxf(fabsf(v.z), fabsf(v.w))));
    }
    red[threadIdx.x] = m;
    __syncthreads();
    for (int s = 128; s > 0; s >>= 1) {
        if (threadIdx.x < s) red[threadIdx.x] = fmaxf(red[threadIdx.x], red[threadIdx.x + s]);
        __syncthreads();
    }
    if (threadIdx.x == 0) atomicMax(slot, __float_as_uint(red[0]));
}

// ---------------- zero the pad regions of xq/a2q (re-poisoned each run) ----------------
__global__ void pad_zero_kernel(char* __restrict__ xq, char* __restrict__ a2q) {
    int hp = blockIdx.x;                 // 0..58
    int n = blockIdx.y;                  // 0..31
    char* base = (blockIdx.z ? a2q : xq) + ((size_t)n * HP + hp) * SLAB;
    int t = threadIdx.x;
    if (hp == 0 || hp >= 57) {           // full pad rows
        f32x4 z = {0.f, 0.f, 0.f, 0.f};
        #pragma unroll
        for (int i = 0; i < 4; ++i) *(f32x4*)(base + (i * 256 + t) * 16) = z;
    } else {                             // column pads: w'=0 and w'=57..63
        long long z8 = 0;
        if (t < 32) {
            *(long long*)(base + t * 8) = z8;
        } else {
            int k = t - 32;              // 0..223 -> 7 chunks of 256B
            int wq_ = 57 + (k >> 5);
            *(long long*)(base + wq_ * 256 + (k & 31) * 8) = z8;
        }
    }
}

// ---------------- weight quant + layout [tap][co][ci] ----------------
__global__ void quant_w_kernel(const float* __restrict__ w, const float* __restrict__ meta,
                               int slot, short* __restrict__ wq) {
    int idx = blockIdx.x * 256 + threadIdx.x;   // 0..16383
    int co = idx >> 7, ci = idx & 127;
    float s = meta[slot] + 1e-12f;
    float qs = 127.f / s;
    const float* src = w + ((size_t)(co * 128 + ci)) * 9;
    #pragma unroll
    for (int tap = 0; tap < 9; ++tap) {
        float q = rintf(src[tap] * qs);
        wq[((size_t)tap * 128 + co) * 128 + ci] = f2bf(q);
    }
}

// ---------------- quantize x (NCHW fp32) -> pre-swizzled padded NHWC bf16 codes ----------------
__global__ void quant_x_kernel(const float* __restrict__ x, const float* __restrict__ meta,
                               char* __restrict__ xq) {
    __shared__ float tile[128][57];
    int h = blockIdx.x, n = blockIdx.y, t = threadIdx.x;
    int ci = t >> 1, seg = (t & 1) * 28;
    const float* row = x + (((size_t)(n * C + ci)) * H + h) * W + seg;
    #pragma unroll
    for (int j = 0; j < 28; j += 4) {
        f32x4 v = *(const f32x4*)(row + j);
        tile[ci][seg + j + 0] = v.x;
        tile[ci][seg + j + 1] = v.y;
        tile[ci][seg + j + 2] = v.z;
        tile[ci][seg + j + 3] = v.w;
    }
    __syncthreads();
    float s = meta[SLOT_SX] + 1e-12f;
    float qs = 127.f / s;
    int w = t & 63, cq = t >> 6;
    if (w < 56) {
        char* slab = xq + ((size_t)n * HP + (h + 1)) * SLAB;
        int wp = w + 1;
        #pragma unroll
        for (int jj = 0; jj < 4; ++jj) {
            bf16x8 v;
            #pragma unroll
            for (int j = 0; j < 8; ++j) {
                float q = rintf(tile[cq * 32 + jj * 8 + j][w] * qs);
                v[j] = f2bf(q);
            }
            int L = wp * 256 + cq * 64 + jj * 16;
            *(bf16x8*)(slab + (L ^ ((wp & 7) << 4))) = v;
        }
    }
}

// ---------------- conv 3x3 implicit-GEMM MFMA, rolling 4-slot LDS window ----------------
// xq: pre-swizzled padded slabs; wq: [tap][co][ci]; y: NHWC bf16 (real units)
// Fused epilogue: per-channel sum/sumsq/max(v)/max(-v) -> meta atomics.
__global__ __launch_bounds__(256) void conv_mfma_kernel(
        const char* __restrict__ xq, const short* __restrict__ wq,
        short* __restrict__ y, float* __restrict__ meta,
        int slot_in, int slot_w, int sum_off, int ssq_off, int maxe_off, int maxneg_off) {
    __shared__ __align__(16) char lds[4 * SLAB];     // 64 KiB
    const int n = blockIdx.y, h0 = blockIdx.x * 4;
    const int t = threadIdx.x, lane = t & 63;
    const int co0 = (t >> 6) * 32, l15 = lane & 15, lg = lane >> 4;

    const char* slabbase = xq + (size_t)n * HP * SLAB;

#define STAGE(s_) { \
    const char* g_ = slabbase + (size_t)(s_) * SLAB; \
    char* l_ = lds + ((s_) & 3) * SLAB; \
    _Pragma("unroll") \
    for (int i_ = 0; i_ < 4; ++i_) { \
        int off_ = (i_ * 256 + t) * 16; \
        __builtin_amdgcn_global_load_lds( \
            (const __attribute__((address_space(1))) unsigned*)(g_ + off_), \
            (__attribute__((address_space(3))) unsigned*)(l_ + off_), 16, 0, 0); } }

    STAGE(h0); STAGE(h0 + 1); STAGE(h0 + 2);         // 12 loads in flight

    float s_in = meta[slot_in] + 1e-12f;
    float s_w  = meta[slot_w] + 1e-12f;
    float dq = s_in * s_w * (1.f / 16129.f);

    float a_sum[8] = {}, a_ssq[8] = {}, a_mx[8], a_mxn[8];
    #pragma unroll
    for (int i = 0; i < 8; ++i) { a_mx[i] = -1e30f; a_mxn[i] = -1e30f; }

    for (int ri = 0; ri < 4; ++ri) {
        int ho = h0 + ri;
        if (ri) __builtin_amdgcn_s_barrier();        // all waves done reading slot to be overwritten
        if (ri < 3) {
            STAGE(ho + 3);                           // prefetch next slab (stays in flight)
            asm volatile("s_waitcnt vmcnt(4)" ::: "memory");   // slabs ho..ho+2 landed
        } else {
            asm volatile("s_waitcnt vmcnt(0)" ::: "memory");
        }
        __builtin_amdgcn_s_barrier();

        f32x4 acc[2][4] = {};
        for (int dh = 0; dh < 3; ++dh) {
            const char* Bb = lds + ((ho + dh) & 3) * SLAB;
            #pragma unroll
            for (int dw = 0; dw < 3; ++dw) {
                const short* wt = wq + (size_t)(dh * 3 + dw) * 16384;
                #pragma unroll
                for (int cc = 0; cc < 4; ++cc) {
                    const short* wp_ = wt + cc * 32 + lg * 8;
                    bf16x8 a0 = *(const bf16x8*)(wp_ + (co0 + l15) * 128);
                    bf16x8 a1 = *(const bf16x8*)(wp_ + (co0 + 16 + l15) * 128);
                    #pragma unroll
                    for (int fj = 0; fj < 4; ++fj) {
                        int wpp = fj * 16 + l15 + dw;
                        int L = (wpp * 256 + cc * 64 + lg * 16) ^ ((wpp & 7) << 4);
                        bf16x8 b = *(const bf16x8*)(Bb + L);
                        acc[0][fj] = __builtin_amdgcn_mfma_f32_16x16x32_bf16(a0, b, acc[0][fj], 0, 0, 0);
                        acc[1][fj] = __builtin_amdgcn_mfma_f32_16x16x32_bf16(a1, b, acc[1][fj], 0, 0, 0);
                    }
                }
            }
        }
        // epilogue: dequant, stats, bf16 NHWC store
        short* yrow = y + (((size_t)n * H + ho) * W) * C;
        #pragma unroll
        for (int ai = 0; ai < 2; ++ai) {
            #pragma unroll
            for (int fj = 0; fj < 4; ++fj) {
                int wo = fj * 16 + l15;
                if (wo < W) {
                    short4v pk;
                    #pragma unroll
                    for (int r = 0; r < 4; ++r) {
                        float v = acc[ai][fj][r] * dq;
                        int si = ai * 4 + r;
                        a_sum[si] += v;
                        a_ssq[si] += v * v;
                        a_mx[si]  = fmaxf(a_mx[si], v);
                        a_mxn[si] = fmaxf(a_mxn[si], -v);
                        pk[r] = f2bf_rne(v);
                    }
                    *(short4v*)(yrow + (size_t)wo * C + co0 + ai * 16 + lg * 4) = pk;
                }
            }
        }
    }
#undef STAGE

    // cross-l15 reduce (16 lanes share a channel set), then one atomic set per wave
    #pragma unroll
    for (int si = 0; si < 8; ++si) {
        float s1 = a_sum[si], s2 = a_ssq[si], m1 = a_mx[si], m2 = a_mxn[si];
        #pragma unroll
        for (int m = 1; m < 16; m <<= 1) {
            s1 += __shfl_xor(s1, m, 64);
            s2 += __shfl_xor(s2, m, 64);
            m1 = fmaxf(m1, __shfl_xor(m1, m, 64));
            m2 = fmaxf(m2, __shfl_xor(m2, m, 64));
        }
        if (l15 == 0) {
            int cch = co0 + (si >> 2) * 16 + lg * 4 + (si & 3);
            atomicAdd(&meta[sum_off + cch], s1);
            atomicAdd(&meta[ssq_off + cch], s2);
            atomicMax((unsigned*)meta + maxe_off + cch, fenc(m1));
            atomicMax((unsigned*)meta + maxneg_off + cch, fenc(m2));
        }
    }
}

// ---------------- BN finalize: scale/shift + analytic quant absmax ----------------
__global__ void bn_finalize_kernel(float* __restrict__ meta, int sum_off, int ssq_off,
                                   int maxe_off, int maxneg_off, int scale_off, int shift_off,
                                   int amax_slot,
                                   const float* __restrict__ gamma, const float* __restrict__ beta) {
    __shared__ float red[128];
    int c = threadIdx.x;   // 128 threads
    float mean = meta[sum_off + c] * (1.f / NHW);
    float var = meta[ssq_off + c] * (1.f / NHW) - mean * mean;
    float istd = rsqrtf(var + 1e-5f);
    float sc = gamma[c] * istd;
    float sh = beta[c] - mean * sc;
    meta[scale_off + c] = sc;
    meta[shift_off + c] = sh;
    if (amax_slot >= 0) {
        float vmax = fdec(((unsigned*)meta)[maxe_off + c]);
        float vmin = -fdec(((unsigned*)meta)[maxneg_off + c]);
        float cand = fmaxf(0.f, fmaxf(sc * vmax + sh, sc * vmin + sh));
        red[c] = cand;
        __syncthreads();
        for (int k = 64; k > 0; k >>= 1) {
            if (c < k) red[c] = fmaxf(red[c], red[c + k]);
            __syncthreads();
        }
        if (c == 0) meta[amax_slot] = red[0];
    }
}

// ---------------- BN+ReLU+quant: y1 (NHWC bf16) -> a2q (pre-swizzled slabs) ----------------
__global__ void quant_bnrelu_kernel(const short* __restrict__ y1, const float* __restrict__ meta,
                                    char* __restrict__ a2q) {
    int h = blockIdx.x, n = blockIdx.y, t = threadIdx.x;
    const short* row = y1 + (((size_t)n * H + h) * W) * C;
    float s = meta[SLOT_SA2] + 1e-12f;
    float qs = 127.f / s;
    char* slab = a2q + ((size_t)n * HP + (h + 1)) * SLAB;
    #pragma unroll
    for (int i = 0; i < 4; ++i) {
        int g = i * 256 + t;
        if (g < 896) {
            int w = g >> 4, cb = (g & 15) * 8;
            bf16x8 v = *(const bf16x8*)(row + g * 8);
            f32x4 sc0 = *(const f32x4*)(meta + SCALE1 + cb);
            f32x4 sc1 = *(const f32x4*)(meta + SCALE1 + cb + 4);
            f32x4 sh0 = *(const f32x4*)(meta + SHIFT1 + cb);
            f32x4 sh1 = *(const f32x4*)(meta + SHIFT1 + cb + 4);
            bf16x8 o;
            #pragma unroll
            for (int j = 0; j < 8; ++j) {
                float sc = (j < 4) ? sc0[j & 3] : sc1[j & 3];
                float sh = (j < 4) ? sh0[j & 3] : sh1[j & 3];
                float a = fmaxf(bf2f(v[j]) * sc + sh, 0.f);
                o[j] = f2bf(rintf(a * qs));
            }
            int wp = w + 1;
            int L = wp * 256 + (g & 15) * 16;
            *(bf16x8*)(slab + (L ^ ((wp & 7) << 4))) = o;
        }
    }
}

// ---------------- final: out = relu(bn2(y2) + x), NHWC bf16 -> NCHW fp32 via LDS ----------------
__global__ void final_kernel(const short* __restrict__ y2, const float* __restrict__ x,
                             const float* __restrict__ meta, float* __restrict__ out) {
    __shared__ short tile[56 * 128];
    int h = blockIdx.x, n = blockIdx.y, t = threadIdx.x;
    const short* row = y2 + (((size_t)n * H + h) * W) * C;
    #pragma unroll
    for (int i = 0; i < 4; ++i) {
        int g = i * 256 + t;
        if (g < 896) *(bf16x8*)(tile + g * 8) = *(const bf16x8*)(row + g * 8);
    }
    __syncthreads();
    int c = t >> 1, seg = (t & 1) * 28;
    float sc = meta[SCALE2 + c], sh = meta[SHIFT2 + c];
    const float* xr = x + (((size_t)(n * C + c)) * H + h) * W + seg;
    float* orow = out + (((size_t)(n * C + c)) * H + h) * W + seg;
    #pragma unroll
    for (int j = 0; j < 28; j += 4) {
        f32x4 xv = *(const f32x4*)(xr + j);
        f32x4 o;
        #pragma unroll
        for (int k = 0; k < 4; ++k) {
            float yv = bf2f(tile[(seg + j + k) * 128 + c]);
            o[k] = fmaxf(yv * sc + sh + xv[k], 0.f);
        }
        *(f32x4*)(orow + j) = o;
    }
}

extern "C" void kernel_launch(void* const* d_in, const int* in_sizes, int n_in,
                              void* d_out, int out_size, void* d_ws, size_t ws_size,
                              hipStream_t stream) {
    const float* x      = (const float*)d_in[0];
    const float* w1     = (const float*)d_in[1];
    const float* gamma1 = (const float*)d_in[2];
    const float* beta1  = (const float*)d_in[3];
    const float* w2     = (const float*)d_in[4];
    const float* gamma2 = (const float*)d_in[5];
    const float* beta2  = (const float*)d_in[6];
    float* out = (float*)d_out;
    char* ws = (char*)d_ws;

    float* meta = (float*)(ws + META_OFF);
    unsigned* metau = (unsigned*)meta;
    char* xq   = ws + XQ_OFF;
    char* a2q  = ws + A2Q_OFF;
    short* y1  = (short*)(ws + Y1_OFF);
    short* y2  = (short*)(ws + Y2_OFF);
    short* w1q = (short*)(ws + W1Q_OFF);
    short* w2q = (short*)(ws + W2Q_OFF);

    hipMemsetAsync(ws + META_OFF, 0, META_BYTES, stream);
    pad_zero_kernel<<<dim3(59, 32, 2), 256, 0, stream>>>(xq, a2q);

    absmax_kernel<<<1024, 256, 0, stream>>>(x, ELTS / 4, metau + SLOT_SX);
    absmax_kernel<<<64, 256, 0, stream>>>(w1, 147456 / 4, metau + SLOT_SW1);
    absmax_kernel<<<64, 256, 0, stream>>>(w2, 147456 / 4, metau + SLOT_SW2);

    quant_w_kernel<<<64, 256, 0, stream>>>(w1, meta, SLOT_SW1, w1q);
    quant_w_kernel<<<64, 256, 0, stream>>>(w2, meta, SLOT_SW2, w2q);

    dim3 ghn(56, 32);
    quant_x_kernel<<<ghn, 256, 0, stream>>>(x, meta, xq);

    dim3 gconv(14, 32);
    conv_mfma_kernel<<<gconv, 256, 0, stream>>>(xq, w1q, y1, meta, SLOT_SX, SLOT_SW1,
                                                SUM1, SSQ1, MAXE1, MAXNEG1);
    bn_finalize_kernel<<<1, 128, 0, stream>>>(meta, SUM1, SSQ1, MAXE1, MAXNEG1,
                                              SCALE1, SHIFT1, SLOT_SA2, gamma1, beta1);
    quant_bnrelu_kernel<<<ghn, 256, 0, stream>>>(y1, meta, a2q);

    conv_mfma_kernel<<<gconv, 256, 0, stream>>>(a2q, w2q, y2, meta, SLOT_SA2, SLOT_SW2,
                                                SUM2, SSQ2, MAXE2, MAXNEG2);
    bn_finalize_kernel<<<1, 128, 0, stream>>>(meta, SUM2, SSQ2, MAXE2, MAXNEG2,
                                              SCALE2, SHIFT2, -1, gamma2, beta2);

    final_kernel<<<ghn, 256, 0, stream>>>(y2, x, meta, out);
}